// Round 7
// baseline (803.126 us; speedup 1.0000x reference)
//
#include <hip/hip_runtime.h>
#include <float.h>
#include <stdint.h>

// SOM2D argmin ||x-w||^2 via split-f16 MFMA. N=32768, M=4096, D=128.
//
// score = ||w||^2 - 2 x.w  (||x||^2 constant per sample: dropped)
// cross = xh*wh + xl*wh + xh*wl  (f16 hi/lo split, fp32 accum; |err|~2e-5)
//
// Round-13: shared-sample block. Empirical co-residency rule from r6/r10/
// r11/r12: LDS budget ~128KB/CU (48KB/block -> only 2 blocks, r12's miss).
// Restructure: all 4 waves of a block share ONE set of 64 samples and
// split the UNIT tiles 4-way. Al (x-lo) stored once, ALL in LDS: 16KB/block
// (+2KB reduce scratch = 18KB -> 4 blocks/CU under any budget theory).
// Each wave's register picture == round-6's (Ah 64, transient bh/bl, acc 32,
// best 32 ~ 116 VGPR <= 128) -> launch_bounds(256,4) caps without forcing
// (r7/r9 capped 50+ below demand; here demand is under the cap).
// Result: 4 waves/SIMD, each from a DIFFERENT block, main loop barrier-free
// -> 4 de-correlated streams; B-load waits + score tails hide under other
// waves' MFMA bursts. Per-SIMD MFMA demand 4x96x17 ~ 6.5k cyc/round now
// saturates the pipe. Main-loop per-tile body is r6's verbatim (the only
// structure the scheduler handles well: r8-r12 all lost to it).
// Cross-wave argmin: per-wave keys -> 2KB LDS -> wave 0 combines; across
// the UG=2 blocks via the r10-verified keys/atomicMin + cnt protocol.

constexpr int D = 128;

typedef _Float16 f16x8 __attribute__((ext_vector_type(8)));
typedef float    f32x4 __attribute__((ext_vector_type(4)));

__device__ __forceinline__ void cvt_split(const float4& a0, const float4& a1,
                                          f16x8& h, f16x8& l) {
    float v[8] = {a0.x, a0.y, a0.z, a0.w, a1.x, a1.y, a1.z, a1.w};
#pragma unroll
    for (int j = 0; j < 8; ++j) {
        _Float16 hh = (_Float16)v[j];
        h[j] = hh;
        l[j] = (_Float16)(v[j] - (float)hh);
    }
}

// W (M x D fp32) -> frag-major hi/lo f16 + wsq. Thread = (unit u, k-octet o).
// Granule slot for (u, k=8o..8o+7), n-tile = 32 units:
//   T=u>>5, t=(u>>4)&1, c=u&15, s=o>>2, q=o&3
//   slot = T*512 + s*128 + t*64 + q*16 + c
// Main-loop read: tile_base(T*512) + s*128 + t*64 + lane. Sequential 1KB/instr.
// Also inits keys (u64 max) and per-sample-group completion counters.
__global__ __launch_bounds__(256) void prep_kernel(
        const float* __restrict__ w, f16x8* __restrict__ hG,
        f16x8* __restrict__ lG, float* __restrict__ wsq, int M,
        unsigned long long* __restrict__ keys, unsigned* __restrict__ cnt,
        int N, int nGroups) {
    int g = blockIdx.x * 256 + threadIdx.x;
    if (keys && g < N) keys[g] = ~0ull;
    if (cnt && g < nGroups) cnt[g] = 0u;
    if (g >= M * 16) return;
    int u = g >> 4, o = g & 15;
    const float4* wp = reinterpret_cast<const float4*>(w + (size_t)u * D + o * 8);
    float4 a0 = wp[0], a1 = wp[1];
    f16x8 h, l;
    cvt_split(a0, a1, h, l);
    float ss = 0.f;
    ss = fmaf(a0.x, a0.x, ss); ss = fmaf(a0.y, a0.y, ss);
    ss = fmaf(a0.z, a0.z, ss); ss = fmaf(a0.w, a0.w, ss);
    ss = fmaf(a1.x, a1.x, ss); ss = fmaf(a1.y, a1.y, ss);
    ss = fmaf(a1.z, a1.z, ss); ss = fmaf(a1.w, a1.w, ss);
#pragma unroll
    for (int m = 1; m < 16; m <<= 1) ss += __shfl_xor(ss, m, 64);
    if (o == 0) wsq[u] = ss;
    int slot = ((u >> 5) << 9) + ((o >> 2) << 7) + (((u >> 4) & 1) << 6)
             + ((o & 3) << 4) + (u & 15);
    hG[slot] = h;
    lG[slot] = l;
}

template <bool PARTIAL>
__global__ __launch_bounds__(256, 4) void som_main(
        const float* __restrict__ x, const f16x8* __restrict__ hG,
        const f16x8* __restrict__ lG, const float* __restrict__ wsq,
        const int* __restrict__ grid, int* __restrict__ out,
        unsigned long long* __restrict__ keys, unsigned* __restrict__ cnt,
        int unitGroups, int tilesPW, int N) {
    // Al (x-lo) for the block's 64 shared samples, written by wave 0 only.
    __shared__ f16x8 albuf[1024];              // 16 KB
    __shared__ unsigned long long red[4 * 64]; // 2 KB cross-wave scratch

    const int tid  = threadIdx.x;
    const int lane = tid & 63;
    const int wv   = tid >> 6;
    const int c    = lane & 15;   // frag col-class
    const int q    = lane >> 4;   // frag quad

    const int ug = blockIdx.x % unitGroups;
    const int sg = blockIdx.x / unitGroups;
    const int s0 = sg * 64;       // the block's 64 samples (shared by all waves)

    // ---- A-frags: 64 samples x K=128, loaded by EVERY wave (same data, L2
    // broadcast; per-wave cost identical to r6). Ah resident (64 VGPRs);
    // Al -> LDS once (wave 0 writes; benign to skip for others).
    // A[m = lane&15][k = q*8 + j], m-tile i in 0..3, k-step s in 0..3.
    f16x8 Ah[16];
#pragma unroll
    for (int i = 0; i < 4; ++i) {
        const float* xr = x + (size_t)(s0 + 16 * i + c) * D + q * 8;
#pragma unroll
        for (int s = 0; s < 4; ++s) {
            float4 a0 = *reinterpret_cast<const float4*>(xr + 32 * s);
            float4 a1 = *reinterpret_cast<const float4*>(xr + 32 * s + 4);
            f16x8 h, l;
            cvt_split(a0, a1, h, l);
            Ah[i * 4 + s] = h;
            if (wv == 0) albuf[(i * 4 + s) * 64 + lane] = l;
        }
    }
    __syncthreads();   // Al visible to all waves; main loop is barrier-free.

    float bestD[16];
    int   bestI[16];
#pragma unroll
    for (int sl = 0; sl < 16; ++sl) { bestD[sl] = FLT_MAX; bestI[sl] = 0; }

    // wave (ug,wv) owns tiles [ (ug*4+wv)*tilesPW, +tilesPW )
    const int tile0 = (ug * 4 + wv) * tilesPW;

    for (int tt = 0; tt < tilesPW; ++tt) {
        const int tile = tile0 + tt;
        const f16x8* hp = hG + ((size_t)tile << 9) + lane;
        const f16x8* lp = lG + ((size_t)tile << 9) + lane;

        // B tile into registers, round-6 source order (compiler sinks/batches
        // these optimally: bh reused by passes 1+2 -> loads amortized).
        f16x8 bh[8], bl[8];
#pragma unroll
        for (int s = 0; s < 4; ++s)
#pragma unroll
            for (int t = 0; t < 2; ++t)
                bh[s * 2 + t] = hp[s * 128 + t * 64];
#pragma unroll
        for (int s = 0; s < 4; ++s)
#pragma unroll
            for (int t = 0; t < 2; ++t)
                bl[s * 2 + t] = lp[s * 128 + t * 64];

        const int uTile = tile * 32;
        const float wq0 = wsq[uTile + c];
        const float wq1 = wsq[uTile + 16 + c];

        f32x4 acc[8];   // [i*2 + t]
#pragma unroll
        for (int f = 0; f < 8; ++f) acc[f] = (f32x4){0.f, 0.f, 0.f, 0.f};

        // pass 1: xh.wh
#pragma unroll
        for (int s = 0; s < 4; ++s)
#pragma unroll
            for (int i = 0; i < 4; ++i)
#pragma unroll
                for (int t = 0; t < 2; ++t)
                    acc[i * 2 + t] = __builtin_amdgcn_mfma_f32_16x16x32_f16(
                        Ah[i * 4 + s], bh[s * 2 + t], acc[i * 2 + t], 0, 0, 0);
        // pass 2: xl.wh (Al from block-shared LDS; broadcast-friendly reads)
#pragma unroll
        for (int s = 0; s < 4; ++s) {
            f16x8 al[4];
#pragma unroll
            for (int i = 0; i < 4; ++i) al[i] = albuf[(i * 4 + s) * 64 + lane];
#pragma unroll
            for (int i = 0; i < 4; ++i)
#pragma unroll
                for (int t = 0; t < 2; ++t)
                    acc[i * 2 + t] = __builtin_amdgcn_mfma_f32_16x16x32_f16(
                        al[i], bh[s * 2 + t], acc[i * 2 + t], 0, 0, 0);
        }
        // pass 3: xh.wl
#pragma unroll
        for (int s = 0; s < 4; ++s)
#pragma unroll
            for (int i = 0; i < 4; ++i)
#pragma unroll
                for (int t = 0; t < 2; ++t)
                    acc[i * 2 + t] = __builtin_amdgcn_mfma_f32_16x16x32_f16(
                        Ah[i * 4 + s], bl[s * 2 + t], acc[i * 2 + t], 0, 0, 0);

        // ---- score + per-lane argmin. C layout: row m = q*4+r (+16i), col = c (+16t).
#pragma unroll
        for (int t = 0; t < 2; ++t) {
            const int n    = uTile + 16 * t + c;
            const float wq = t == 0 ? wq0 : wq1;
#pragma unroll
            for (int i = 0; i < 4; ++i) {
                f32x4 a = acc[i * 2 + t];
#pragma unroll
                for (int r = 0; r < 4; ++r) {
                    float score = fmaf(-2.f, a[r], wq);
                    int sl = i * 4 + r;
                    if (score < bestD[sl]) { bestD[sl] = score; bestI[sl] = n; }
                }
            }
        }
    }

    // ---- per-wave reduce over the 16 col-classes, result -> LDS scratch ----
#pragma unroll
    for (int sl = 0; sl < 16; ++sl) {
        float d   = bestD[sl];
        int   idx = bestI[sl];
#pragma unroll
        for (int m = 1; m < 16; m <<= 1) {
            float od = __shfl_xor(d, m, 64);
            int   oi = __shfl_xor(idx, m, 64);
            if (od < d || (od == d && oi < idx)) { d = od; idx = oi; }
        }
        if (c == 0) {
            const int loc = 16 * (sl >> 2) + 4 * q + (sl & 3);   // 0..63
            unsigned ub = __float_as_uint(d);
            ub = (ub & 0x80000000u) ? ~ub : (ub | 0x80000000u);  // monotone map
            red[wv * 64 + loc] = ((unsigned long long)ub << 32) | (unsigned)idx;
        }
    }
    __syncthreads();

    // ---- wave 0: combine the 4 waves' candidates; then cross-block ----
    if (wv == 0) {
        unsigned long long k = red[lane];
#pragma unroll
        for (int w = 1; w < 4; ++w) {
            unsigned long long kw = red[w * 64 + lane];
            if (kw < k) k = kw;
        }
        const int sOut = s0 + lane;
        if (PARTIAL) {
            atomicMin(&keys[sOut], k);
            // release: this wave's atomics precede the counter bump.
            __threadfence();
            int old = 0;
            if (lane == 0) old = (int)atomicAdd(&cnt[sg], 1u);
            old = __shfl(old, 0, 64);
            if (old == unitGroups - 1) {
                __threadfence();   // acquire
                unsigned long long kf = atomicMin(&keys[sOut], ~0ull);  // atomic read
                int idx = (int)(unsigned)(kf & 0xFFFFFFFFull);
                out[2 * sOut]     = grid[2 * idx];
                out[2 * sOut + 1] = grid[2 * idx + 1];
            }
        } else {
            int idx = (int)(unsigned)(k & 0xFFFFFFFFull);
            out[2 * sOut]     = grid[2 * idx];
            out[2 * sOut + 1] = grid[2 * idx + 1];
        }
    }
}

extern "C" void kernel_launch(void* const* d_in, const int* in_sizes, int n_in,
                              void* d_out, int out_size, void* d_ws, size_t ws_size,
                              hipStream_t stream) {
    const float* x    = (const float*)d_in[0];
    const float* w    = (const float*)d_in[1];
    const int*   grid = (const int*)d_in[2];
    int* out = (int*)d_out;

    const int N = in_sizes[0] / D;   // 32768
    const int M = in_sizes[1] / D;   // 4096

    // ws layout: hG (1 MB) | lG (1 MB) | wsq (16 KB) | keys (N*8) | cnt
    const size_t hlBytes   = (size_t)M * D * 2;
    const size_t baseBytes = 2 * hlBytes + (size_t)M * 4;
    const int sampleGroups = N / 64;    // blocks of 4 waves sharing 64 samples
    const size_t needBytes = baseBytes + (size_t)N * 8 + (size_t)sampleGroups * 4;

    f16x8* hG  = (f16x8*)d_ws;
    f16x8* lG  = (f16x8*)((char*)d_ws + hlBytes);
    float* wsq = (float*)((char*)d_ws + 2 * hlBytes);
    unsigned long long* keys = (unsigned long long*)((char*)d_ws + baseBytes);
    unsigned* cnt = (unsigned*)((char*)d_ws + baseBytes + (size_t)N * 8);

    const int tiles = M / 32;           // 128 tiles of 32 units
    const int UG = (ws_size >= needBytes) ? 2 : 1;   // 2 -> 1024 blocks = 4/CU

    prep_kernel<<<(M * 16 + 255) / 256, 256, 0, stream>>>(
        w, hG, lG, wsq, M,
        UG > 1 ? keys : nullptr, UG > 1 ? cnt : nullptr, N, sampleGroups);

    const int tilesPW = tiles / (4 * UG);   // UG=2: 16, UG=1: 32 (both exact)
    if (UG > 1) {
        som_main<true><<<sampleGroups * UG, 256, 0, stream>>>(
            x, hG, lG, wsq, grid, out, keys, cnt, UG, tilesPW, N);
    } else {
        som_main<false><<<sampleGroups, 256, 0, stream>>>(
            x, hG, lG, wsq, grid, out, nullptr, nullptr, 1, tilesPW, N);
    }
}

// Round 8
// 497.787 us; speedup vs baseline: 1.6134x; 1.6134x over previous
//
#include <hip/hip_runtime.h>
#include <float.h>
#include <stdint.h>

// SOM2D argmin ||x-w||^2 via split-f16 MFMA. N=32768, M=4096, D=128.
//
// Round-14: cut the WORK, not the schedule. r7/r9/r13 proved forcing >2
// waves/SIMD spills; r8/r10/r11 proved restructuring the 3-pass loses to
// the compiler's own schedule (r6: 96us, MfmaUtil 48%). New plan:
//   sweep1 (som_hi): hi-pass only (32 MFMA/tile, hG only) + per-sample
//     best1/best2 tracking. Sound bound: |S_hi - S_ref| <= E,
//     E = 2(||xl||(maxWH+maxWL) + ||xh||*maxWL) + pad  (Cauchy-Schwarz;
//     pad 0.02 covers MFMA/ref fp32 accum rounding, ~40x margin).
//     If best2-best1 > 2E the hi-winner is PROVEN = reference argmin ->
//     write out. Else flag the sample (expected ~3-8%).
//   sweep2 (som_fix): the r6 3-pass kernel (verbatim tile body, 7 rounds
//     at absmax 0) on flagged samples only, via compacted list, grid-
//     strided -> correct at ANY flag rate.
// Cross-block 2-best merge: per-(ug,sample) partials (monotone-u64 b1key,
// monotone-u32 b2) via atomicExch; r10-verified cnt[]+threadfence
// protocol; last contributor merges, decides flag, writes out or appends
// to flagList. w-norm maxima from prep via block-reduced atomicMax.

constexpr int D = 128;

typedef _Float16 f16x8 __attribute__((ext_vector_type(8)));
typedef float    f32x4 __attribute__((ext_vector_type(4)));

__device__ __forceinline__ void cvt_split(const float4& a0, const float4& a1,
                                          f16x8& h, f16x8& l) {
    float v[8] = {a0.x, a0.y, a0.z, a0.w, a1.x, a1.y, a1.z, a1.w};
#pragma unroll
    for (int j = 0; j < 8; ++j) {
        _Float16 hh = (_Float16)v[j];
        h[j] = hh;
        l[j] = (_Float16)(v[j] - (float)hh);
    }
}

// monotone float<->uint map (total order preserving, incl. negatives)
__device__ __forceinline__ unsigned monoU(float f) {
    unsigned u = __float_as_uint(f);
    return (u & 0x80000000u) ? ~u : (u | 0x80000000u);
}
__device__ __forceinline__ float monoF(unsigned t) {
    unsigned b = (t & 0x80000000u) ? (t ^ 0x80000000u) : ~t;
    return __uint_as_float(b);
}

__global__ void init_kernel(unsigned* scal, unsigned* cnt, int nGroups) {
    int t = threadIdx.x;
    if (t < 4) scal[t] = 0u;                 // maxWH2, maxWL2, flagCnt, pad
    for (int i = t; i < nGroups; i += 256) cnt[i] = 0u;
}

// W (M x D fp32) -> frag-major hi/lo f16 + wsq + global max ||wh||^2,||wl||^2.
// Thread = (unit u, k-octet o). Granule slot (32-unit tiles):
//   T=u>>5, t=(u>>4)&1, c=u&15, s=o>>2, q=o&3
//   slot = T*512 + s*128 + t*64 + q*16 + c
__global__ __launch_bounds__(256) void prep_kernel(
        const float* __restrict__ w, f16x8* __restrict__ hG,
        f16x8* __restrict__ lG, float* __restrict__ wsq, int M,
        unsigned* __restrict__ scal) {
    int g = blockIdx.x * 256 + threadIdx.x;
    if (g >= M * 16) return;
    int u = g >> 4, o = g & 15;
    const float4* wp = reinterpret_cast<const float4*>(w + (size_t)u * D + o * 8);
    float4 a0 = wp[0], a1 = wp[1];
    f16x8 h, l;
    cvt_split(a0, a1, h, l);
    float ss = 0.f, hs = 0.f, ls = 0.f;
    ss = fmaf(a0.x, a0.x, ss); ss = fmaf(a0.y, a0.y, ss);
    ss = fmaf(a0.z, a0.z, ss); ss = fmaf(a0.w, a0.w, ss);
    ss = fmaf(a1.x, a1.x, ss); ss = fmaf(a1.y, a1.y, ss);
    ss = fmaf(a1.z, a1.z, ss); ss = fmaf(a1.w, a1.w, ss);
#pragma unroll
    for (int j = 0; j < 8; ++j) {
        float hf = (float)h[j], lf = (float)l[j];
        hs = fmaf(hf, hf, hs);
        ls = fmaf(lf, lf, ls);
    }
#pragma unroll
    for (int m = 1; m < 16; m <<= 1) {
        ss += __shfl_xor(ss, m, 64);
        hs += __shfl_xor(hs, m, 64);
        ls += __shfl_xor(ls, m, 64);
    }
    if (o == 0) wsq[u] = ss;
    if (scal) {
        // wave-level max, one atomic per wave per scalar
        float hm = hs, lm = ls;
        hm = fmaxf(hm, __shfl_xor(hm, 16, 64)); hm = fmaxf(hm, __shfl_xor(hm, 32, 64));
        lm = fmaxf(lm, __shfl_xor(lm, 16, 64)); lm = fmaxf(lm, __shfl_xor(lm, 32, 64));
        if ((threadIdx.x & 63) == 0) {
            atomicMax(&scal[0], __float_as_uint(hm));   // positive: bit-monotone
            atomicMax(&scal[1], __float_as_uint(lm));
        }
    }
    int slot = ((u >> 5) << 9) + ((o >> 2) << 7) + (((u >> 4) & 1) << 6)
             + ((o & 3) << 4) + (u & 15);
    hG[slot] = h;
    lG[slot] = l;
}

// sweep1: hi-pass only + best1/best2 + soundness flag.
template <int UGT>
__global__ __launch_bounds__(256, 2) void som_hi(
        const float* __restrict__ x, const f16x8* __restrict__ hG,
        const float* __restrict__ wsq, const int* __restrict__ grid,
        int* __restrict__ out, const unsigned* __restrict__ scal,
        unsigned long long* __restrict__ b1key, unsigned* __restrict__ b2u,
        float* __restrict__ thrS, unsigned* __restrict__ cnt,
        unsigned* __restrict__ flagCnt, int* __restrict__ flagList,
        int tilesPer, int N) {
    const int tid  = threadIdx.x;
    const int lane = tid & 63;
    const int wv   = tid >> 6;
    const int c    = lane & 15;
    const int q    = lane >> 4;

    const int ug    = blockIdx.x % UGT;
    const int sg    = blockIdx.x / UGT;
    const int sWave = sg * 256 + wv * 64;

    const float maxWH = sqrtf(__uint_as_float(scal[0]));
    const float maxWL = sqrtf(__uint_as_float(scal[1]));

    // A hi-frags (64 VGPRs) + per-sample threshold 2E -> thrS.
    f16x8 Ah[16];
#pragma unroll
    for (int i = 0; i < 4; ++i) {
        const float* xr = x + (size_t)(sWave + 16 * i + c) * D + q * 8;
        float xh2 = 0.f, xl2 = 0.f;
#pragma unroll
        for (int s = 0; s < 4; ++s) {
            float4 a0 = *reinterpret_cast<const float4*>(xr + 32 * s);
            float4 a1 = *reinterpret_cast<const float4*>(xr + 32 * s + 4);
            f16x8 h, l;
            cvt_split(a0, a1, h, l);
            Ah[i * 4 + s] = h;
#pragma unroll
            for (int j = 0; j < 8; ++j) {
                float hf = (float)h[j], lf = (float)l[j];
                xh2 = fmaf(hf, hf, xh2);
                xl2 = fmaf(lf, lf, xl2);
            }
        }
        xh2 += __shfl_xor(xh2, 16, 64); xh2 += __shfl_xor(xh2, 32, 64);
        xl2 += __shfl_xor(xl2, 16, 64); xl2 += __shfl_xor(xl2, 32, 64);
        if (q == 0)   // threshold = 2E; E = 2(||xl||(WH+WL)+||xh||WL)+pad
            thrS[sWave + 16 * i + c] =
                4.0f * (sqrtf(xl2) * (maxWH + maxWL) + sqrtf(xh2) * maxWL) + 0.04f;
    }

    float b1d[16]; int b1i[16]; float b2d[16];
#pragma unroll
    for (int sl = 0; sl < 16; ++sl) { b1d[sl] = FLT_MAX; b1i[sl] = 0; b2d[sl] = FLT_MAX; }

    const int tile0 = ug * tilesPer;
    for (int tt = 0; tt < tilesPer; ++tt) {
        const int tile = tile0 + tt;
        const f16x8* hp = hG + ((size_t)tile << 9) + lane;

        f16x8 bh[8];
#pragma unroll
        for (int s = 0; s < 4; ++s)
#pragma unroll
            for (int t = 0; t < 2; ++t)
                bh[s * 2 + t] = hp[s * 128 + t * 64];

        const int uTile = tile * 32;
        const float wq0 = wsq[uTile + c];
        const float wq1 = wsq[uTile + 16 + c];

        f32x4 acc[8];
#pragma unroll
        for (int f = 0; f < 8; ++f) acc[f] = (f32x4){0.f, 0.f, 0.f, 0.f};

#pragma unroll
        for (int s = 0; s < 4; ++s)
#pragma unroll
            for (int i = 0; i < 4; ++i)
#pragma unroll
                for (int t = 0; t < 2; ++t)
                    acc[i * 2 + t] = __builtin_amdgcn_mfma_f32_16x16x32_f16(
                        Ah[i * 4 + s], bh[s * 2 + t], acc[i * 2 + t], 0, 0, 0);

        // score + 2-best. C layout: row m = q*4+r (+16i), col = c (+16t).
#pragma unroll
        for (int t = 0; t < 2; ++t) {
            const int n    = uTile + 16 * t + c;
            const float wq = t == 0 ? wq0 : wq1;
#pragma unroll
            for (int i = 0; i < 4; ++i) {
                f32x4 a = acc[i * 2 + t];
#pragma unroll
                for (int r = 0; r < 4; ++r) {
                    float v = fmaf(-2.f, a[r], wq);
                    int sl = i * 4 + r;
                    if (v < b1d[sl]) { b2d[sl] = b1d[sl]; b1d[sl] = v; b1i[sl] = n; }
                    else if (v < b2d[sl]) b2d[sl] = v;
                }
            }
        }
    }

    // cross-lane (16-group) merge of (b1,b2) pairs
#pragma unroll
    for (int sl = 0; sl < 16; ++sl) {
        float d1 = b1d[sl]; int i1 = b1i[sl]; float d2 = b2d[sl];
#pragma unroll
        for (int m = 1; m < 16; m <<= 1) {
            float od1 = __shfl_xor(d1, m, 64);
            int   oi1 = __shfl_xor(i1, m, 64);
            float od2 = __shfl_xor(d2, m, 64);
            float nd2 = fminf(fminf(d2, od2), fmaxf(d1, od1));
            bool take = od1 < d1 || (od1 == d1 && oi1 < i1);
            d1 = take ? od1 : d1;
            i1 = take ? oi1 : i1;
            d2 = nd2;
        }
        if (c == 0) {
            const int sOut = sWave + 16 * (sl >> 2) + 4 * q + (sl & 3);
            unsigned long long k = ((unsigned long long)monoU(d1) << 32) | (unsigned)i1;
            atomicExch(&b1key[(size_t)ug * N + sOut], k);   // atomic: coherency
            atomicExch(&b2u[(size_t)ug * N + sOut], monoU(d2));
        }
    }

    // completion protocol (r10-verified): last of 4*UGT waves merges the group.
    __threadfence();
    int old = 0;
    if (lane == 0) old = (int)atomicAdd(&cnt[sg], 1u);
    old = __shfl(old, 0, 64);
    if (old == 4 * UGT - 1) {
        __threadfence();
#pragma unroll
        for (int j = 0; j < 4; ++j) {
            const int s = sg * 256 + j * 64 + lane;
            unsigned long long k[UGT]; unsigned u2[UGT];
#pragma unroll
            for (int g2 = 0; g2 < UGT; ++g2) {
                k[g2]  = atomicMin(&b1key[(size_t)g2 * N + s], ~0ull);       // atomic read
                u2[g2] = atomicMin(&b2u[(size_t)g2 * N + s], 0xFFFFFFFFu);   // atomic read
            }
            unsigned long long g1 = k[0];
#pragma unroll
            for (int g2 = 1; g2 < UGT; ++g2) if (k[g2] < g1) g1 = k[g2];
            unsigned gb2 = 0xFFFFFFFFu;
#pragma unroll
            for (int g2 = 0; g2 < UGT; ++g2) {
                unsigned hi = (unsigned)(k[g2] >> 32);
                if (k[g2] != g1 && hi < gb2) gb2 = hi;   // losing b1 -> b2 candidate
                if (u2[g2] < gb2) gb2 = u2[g2];
            }
            float d1 = monoF((unsigned)(g1 >> 32));
            float d2 = monoF(gb2);
            if (d2 - d1 > thrS[s]) {        // proven winner
                int idx = (int)(unsigned)(g1 & 0xFFFFFFFFull);
                out[2 * s]     = grid[2 * idx];
                out[2 * s + 1] = grid[2 * idx + 1];
            } else {                        // ambiguous under bound -> refine
                unsigned pos = atomicAdd(flagCnt, 1u);
                flagList[pos] = s;
            }
        }
    }
}

// sweep2 / fallback: r6's verified 3-pass tile body; GATHER -> flagged list.
template <bool GATHER>
__global__ __launch_bounds__(256, 2) void som_fix(
        const float* __restrict__ x, const f16x8* __restrict__ hG,
        const f16x8* __restrict__ lG, const float* __restrict__ wsq,
        const int* __restrict__ grid, int* __restrict__ out,
        const int* __restrict__ flagList, const unsigned* __restrict__ totalPtr,
        int totalN, int tiles) {
    __shared__ f16x8 albuf[4 * 1024];   // 64 KB, wave-private slices

    const int tid  = threadIdx.x;
    const int lane = tid & 63;
    const int wv   = tid >> 6;
    const int c    = lane & 15;
    const int q    = lane >> 4;

    const int total = GATHER ? (int)totalPtr[0] : totalN;
    f16x8* myAl = &albuf[wv * 1024];

    for (int base = blockIdx.x * 256; base < total; base += gridDim.x * 256) {
        const int sBase = base + wv * 64;

        f16x8 Ah[16];
#pragma unroll
        for (int i = 0; i < 4; ++i) {
            int p = sBase + 16 * i + c;
            int s = GATHER ? flagList[p < total ? p : total - 1] : p;
            const float* xr = x + (size_t)s * D + q * 8;
#pragma unroll
            for (int ks = 0; ks < 4; ++ks) {
                float4 a0 = *reinterpret_cast<const float4*>(xr + 32 * ks);
                float4 a1 = *reinterpret_cast<const float4*>(xr + 32 * ks + 4);
                f16x8 h, l;
                cvt_split(a0, a1, h, l);
                Ah[i * 4 + ks] = h;
                myAl[(i * 4 + ks) * 64 + lane] = l;   // own slice: no barrier
            }
        }

        float bestD[16]; int bestI[16];
#pragma unroll
        for (int sl = 0; sl < 16; ++sl) { bestD[sl] = FLT_MAX; bestI[sl] = 0; }

        for (int tile = 0; tile < tiles; ++tile) {
            const f16x8* hp = hG + ((size_t)tile << 9) + lane;
            const f16x8* lp = lG + ((size_t)tile << 9) + lane;

            f16x8 bh[8], bl[8];
#pragma unroll
            for (int s = 0; s < 4; ++s)
#pragma unroll
                for (int t = 0; t < 2; ++t) {
                    bh[s * 2 + t] = hp[s * 128 + t * 64];
                    bl[s * 2 + t] = lp[s * 128 + t * 64];
                }

            const int uTile = tile * 32;
            const float wq0 = wsq[uTile + c];
            const float wq1 = wsq[uTile + 16 + c];

            f32x4 acc[8];
#pragma unroll
            for (int f = 0; f < 8; ++f) acc[f] = (f32x4){0.f, 0.f, 0.f, 0.f};

#pragma unroll
            for (int s = 0; s < 4; ++s)
#pragma unroll
                for (int i = 0; i < 4; ++i)
#pragma unroll
                    for (int t = 0; t < 2; ++t)
                        acc[i * 2 + t] = __builtin_amdgcn_mfma_f32_16x16x32_f16(
                            Ah[i * 4 + s], bh[s * 2 + t], acc[i * 2 + t], 0, 0, 0);
#pragma unroll
            for (int s = 0; s < 4; ++s) {
                f16x8 al[4];
#pragma unroll
                for (int i = 0; i < 4; ++i) al[i] = myAl[(i * 4 + s) * 64 + lane];
#pragma unroll
                for (int i = 0; i < 4; ++i)
#pragma unroll
                    for (int t = 0; t < 2; ++t)
                        acc[i * 2 + t] = __builtin_amdgcn_mfma_f32_16x16x32_f16(
                            al[i], bh[s * 2 + t], acc[i * 2 + t], 0, 0, 0);
            }
#pragma unroll
            for (int s = 0; s < 4; ++s)
#pragma unroll
                for (int i = 0; i < 4; ++i)
#pragma unroll
                    for (int t = 0; t < 2; ++t)
                        acc[i * 2 + t] = __builtin_amdgcn_mfma_f32_16x16x32_f16(
                            Ah[i * 4 + s], bl[s * 2 + t], acc[i * 2 + t], 0, 0, 0);

#pragma unroll
            for (int t = 0; t < 2; ++t) {
                const int n    = uTile + 16 * t + c;
                const float wq = t == 0 ? wq0 : wq1;
#pragma unroll
                for (int i = 0; i < 4; ++i) {
                    f32x4 a = acc[i * 2 + t];
#pragma unroll
                    for (int r = 0; r < 4; ++r) {
                        float score = fmaf(-2.f, a[r], wq);
                        int sl = i * 4 + r;
                        if (score < bestD[sl]) { bestD[sl] = score; bestI[sl] = n; }
                    }
                }
            }
        }

#pragma unroll
        for (int sl = 0; sl < 16; ++sl) {
            float d   = bestD[sl];
            int   idx = bestI[sl];
#pragma unroll
            for (int m = 1; m < 16; m <<= 1) {
                float od = __shfl_xor(d, m, 64);
                int   oi = __shfl_xor(idx, m, 64);
                if (od < d || (od == d && oi < idx)) { d = od; idx = oi; }
            }
            if (c == 0) {
                int p2 = sBase + 16 * (sl >> 2) + 4 * q + (sl & 3);
                int s2 = GATHER ? flagList[p2 < total ? p2 : total - 1] : p2;
                out[2 * s2]     = grid[2 * idx];    // dup writes: same value
                out[2 * s2 + 1] = grid[2 * idx + 1];
            }
        }
    }
}

extern "C" void kernel_launch(void* const* d_in, const int* in_sizes, int n_in,
                              void* d_out, int out_size, void* d_ws, size_t ws_size,
                              hipStream_t stream) {
    const float* x    = (const float*)d_in[0];
    const float* w    = (const float*)d_in[1];
    const int*   grid = (const int*)d_in[2];
    int* out = (int*)d_out;

    const int N = in_sizes[0] / D;   // 32768
    const int M = in_sizes[1] / D;   // 4096
    const int UG      = 4;
    const int tiles   = M / 32;          // 128
    const int nGroups = N / 256;         // 128

    // ws layout
    const size_t hlB    = (size_t)M * D * 2;          // 1 MB each
    const size_t oWsq   = 2 * hlB;                    // M*4
    const size_t oScal  = oWsq + (size_t)M * 4;       // 4 u32 (pad 32)
    const size_t oCnt   = oScal + 32;                 // nGroups u32
    const size_t oThr   = oCnt + (size_t)nGroups * 4; // N f32
    const size_t oB1    = oThr + (size_t)N * 4;       // UG*N u64
    const size_t oB2    = oB1 + (size_t)UG * N * 8;   // UG*N u32
    const size_t oFlag  = oB2 + (size_t)UG * N * 4;   // N i32
    const size_t need   = oFlag + (size_t)N * 4;

    f16x8* hG  = (f16x8*)d_ws;
    f16x8* lG  = (f16x8*)((char*)d_ws + hlB);
    float* wsq = (float*)((char*)d_ws + oWsq);
    unsigned* scal = (unsigned*)((char*)d_ws + oScal);
    unsigned* cnt  = (unsigned*)((char*)d_ws + oCnt);
    float* thrS    = (float*)((char*)d_ws + oThr);
    unsigned long long* b1key = (unsigned long long*)((char*)d_ws + oB1);
    unsigned* b2u  = (unsigned*)((char*)d_ws + oB2);
    int* flagList  = (int*)((char*)d_ws + oFlag);

    if (ws_size >= need) {
        init_kernel<<<1, 256, 0, stream>>>(scal, cnt, nGroups);
        prep_kernel<<<(M * 16 + 255) / 256, 256, 0, stream>>>(w, hG, lG, wsq, M, scal);
        som_hi<4><<<nGroups * UG, 256, 0, stream>>>(
            x, hG, wsq, grid, out, scal, b1key, b2u, thrS, cnt,
            &scal[2], flagList, tiles / UG, N);
        som_fix<true><<<128, 256, 0, stream>>>(
            x, hG, lG, wsq, grid, out, flagList, &scal[2], 0, tiles);
    } else {
        prep_kernel<<<(M * 16 + 255) / 256, 256, 0, stream>>>(w, hG, lG, wsq, M, nullptr);
        som_fix<false><<<N / 256, 256, 0, stream>>>(
            x, hG, lG, wsq, grid, out, nullptr, nullptr, N, tiles);
    }
}